// Round 2
// baseline (660.552 us; speedup 1.0000x reference)
//
#include <hip/hip_runtime.h>

// ---------- types ----------
typedef short short8 __attribute__((ext_vector_type(8)));   // 8 bf16 as i16
typedef float f32x4 __attribute__((ext_vector_type(4)));

#define GLOBAL_AS __attribute__((address_space(1)))
#define LDS_AS    __attribute__((address_space(3)))

__device__ __forceinline__ unsigned short f2bf(float f) {
    unsigned u = __builtin_bit_cast(unsigned, f);
    u += 0x7fffu + ((u >> 16) & 1u);          // round-to-nearest-even
    return (unsigned short)(u >> 16);
}

// ---------- convert kernels (memory-bound, vectorized) ----------
__global__ __launch_bounds__(256) void k_idx2bf(const int* __restrict__ idx,
                                                const float* __restrict__ cb,
                                                ushort* __restrict__ out, int n4) {
    int i = blockIdx.x * 256 + threadIdx.x;
    if (i >= n4) return;
    int4 v = reinterpret_cast<const int4*>(idx)[i];
    ushort4 o;
    o.x = f2bf(cb[v.x]); o.y = f2bf(cb[v.y]);
    o.z = f2bf(cb[v.z]); o.w = f2bf(cb[v.w]);
    reinterpret_cast<ushort4*>(out)[i] = o;
}

__global__ __launch_bounds__(256) void k_f2bf(const float* __restrict__ in,
                                              ushort* __restrict__ out, int n4) {
    int i = blockIdx.x * 256 + threadIdx.x;
    if (i >= n4) return;
    float4 v = reinterpret_cast<const float4*>(in)[i];
    ushort4 o;
    o.x = f2bf(v.x); o.y = f2bf(v.y); o.z = f2bf(v.z); o.w = f2bf(v.w);
    reinterpret_cast<ushort4*>(out)[i] = o;
}

// ---------- 256x256 8-phase bf16 gemm_bt: C[M,N] = A[M,K]*B[N,K]^T ----------
// 512 thr = 8 waves (2M x 4N), per-wave out 128x64, BK=64, 2 K-tile LDS dbuf
// (128 KiB), st_16x32 swizzle (byte ^= ((byte>>9)&1)<<5) via pre-swizzled
// global source + swizzled ds_read. Counted vmcnt(4) once per K-tile.
// Region schedule per tile t (quadrants Q(mh,nh) at phases 1..4):
//   ph1 Q(0,0) + stage t+1 A-late  -> buf[t+1&1]   (regions idle since t-1)
//   ph2 Q(0,1) + stage t+1 B-late  -> buf[t+1&1]
//   ph3 Q(1,0) + stage t+2 A-early -> buf[t&1]     (A-half0 last read ph2)
//   ph4 Q(1,1) + stage t+2 B-early -> buf[t&1]     (B-half0 last read ph3)
//   fence vmcnt(4): everything except t+2 early halves complete -> t+1 ready.
// A-early rows: 0-63,128-191 (chunks 0-7,16-23); B-early rows: 0-31,64-95,
// 128-159,192-223 (chunks 0-3,8-11,16-19,24-27); chunk = 8 rows = 1024 B.

#define CH_AE(j) ((((j) & 8) << 1) | ((j) & 7))
#define CH_AL(j) (CH_AE(j) + 8)
#define CH_BE(j) ((((j) & 12) << 1) | ((j) & 3))
#define CH_BL(j) (CH_BE(j) + 4)

#define STAGE2(G, LDSBASE, KB, CF) do {                                         \
    const int c0_ = CF(2 * w), c1_ = CF(2 * w + 1);                             \
    __builtin_amdgcn_global_load_lds(                                           \
        (const GLOBAL_AS void*)((G) + (size_t)(c0_ * 8 + srow8) * 4096 + (KB) + scol), \
        (LDS_AS void*)((LDSBASE) + c0_ * 512), 16, 0, 0);                       \
    __builtin_amdgcn_global_load_lds(                                           \
        (const GLOBAL_AS void*)((G) + (size_t)(c1_ * 8 + srow8) * 4096 + (KB) + scol), \
        (LDS_AS void*)((LDSBASE) + c1_ * 512), 16, 0, 0);                       \
} while (0)

#define PHASE(MH, NH, ...) do {                                                 \
    short8 af_[2][4], bf_[2][2];                                                \
    _Pragma("unroll")                                                           \
    for (int k2 = 0; k2 < 2; ++k2) {                                            \
        _Pragma("unroll")                                                       \
        for (int mi = 0; mi < 4; ++mi) {                                        \
            const int lb = (arow + (MH) * 64 + mi * 16) * 128 + k2 * 64 + fkb;  \
            af_[k2][mi] = *reinterpret_cast<const short8*>((const char*)At + (lb ^ swb)); \
        }                                                                       \
        _Pragma("unroll")                                                       \
        for (int ni = 0; ni < 2; ++ni) {                                        \
            const int lb = (brow + (NH) * 32 + ni * 16) * 128 + k2 * 64 + fkb;  \
            bf_[k2][ni] = *reinterpret_cast<const short8*>((const char*)Bt + (lb ^ swb)); \
        }                                                                       \
    }                                                                           \
    __VA_ARGS__;                                                                \
    asm volatile("" ::: "memory");                                              \
    __builtin_amdgcn_s_barrier();                                               \
    __builtin_amdgcn_s_setprio(1);                                              \
    __builtin_amdgcn_sched_barrier(0);                                          \
    _Pragma("unroll")                                                           \
    for (int k2 = 0; k2 < 2; ++k2)                                              \
        _Pragma("unroll")                                                       \
        for (int mi = 0; mi < 4; ++mi)                                          \
            _Pragma("unroll")                                                   \
            for (int ni = 0; ni < 2; ++ni)                                      \
                acc[(MH) * 4 + mi][(NH) * 2 + ni] =                             \
                    __builtin_amdgcn_mfma_f32_16x16x32_bf16(                    \
                        af_[k2][mi], bf_[k2][ni], acc[(MH) * 4 + mi][(NH) * 2 + ni], 0, 0, 0); \
    __builtin_amdgcn_sched_barrier(0);                                          \
    __builtin_amdgcn_s_setprio(0);                                              \
    asm volatile("" ::: "memory");                                              \
    __builtin_amdgcn_s_barrier();                                               \
    asm volatile("" ::: "memory");                                              \
} while (0)

// EPI=0: C=bf16, val = acc * extra[row]; EPI=1: C=f32, val = acc + extra[col]
template <int EPI>
__global__ __launch_bounds__(512, 2) void gemm256(const ushort* __restrict__ A,
                                                  const ushort* __restrict__ B,
                                                  void* __restrict__ C,
                                                  const float* __restrict__ extra) {
    constexpr int K = 4096, N = 4096, NT = K / 64;
    __shared__ ushort sA[2][256 * 64];
    __shared__ ushort sB[2][256 * 64];

    const int tid  = threadIdx.x;
    const int w    = tid >> 6;
    const int lane = tid & 63;
    const int wm = w >> 2, wn = w & 3;

    // XCD-aware swizzle (nwg % 8 == 0 for both grids)
    const int nwg = gridDim.x;
    const int sw  = ((int)blockIdx.x & 7) * (nwg >> 3) + ((int)blockIdx.x >> 3);
    const int m0 = (sw >> 4) * 256;      // N/256 == 16 tiles per row
    const int n0 = (sw & 15) * 256;

    const ushort* gA = A + (size_t)m0 * K;
    const ushort* gB = B + (size_t)n0 * K;

    // staging lane geometry: dest = chunk*1024 + lane*16 (linear);
    // source column pre-swizzled so that phys^((phys>>9)&1)<<5 holds it
    const int srow8 = lane >> 3;
    const int scol  = ((lane & 7) * 8) ^ (((lane >> 5) & 1) << 4);   // ushorts

    // fragment geometry (16x16x32: row=lane&15, k=(lane>>4)*8)
    const int fr   = lane & 15;
    const int fkb  = ((lane >> 4) & 3) * 16;          // byte offset along K
    const int swb  = ((fr >> 2) & 1) << 5;            // read-side swizzle XOR
    const int arow = wm * 128 + fr;
    const int brow = wn * 64 + fr;

    f32x4 acc[8][4];
#pragma unroll
    for (int i = 0; i < 8; ++i)
#pragma unroll
        for (int j = 0; j < 4; ++j) acc[i][j] = (f32x4){0.f, 0.f, 0.f, 0.f};

    // ---- prologue: tile0 (all) -> buf0; tile1 (early) -> buf1 ----
    STAGE2(gA, sA[0], 0, CH_AE);  STAGE2(gB, sB[0], 0, CH_BE);
    STAGE2(gA, sA[0], 0, CH_AL);  STAGE2(gB, sB[0], 0, CH_BL);
    STAGE2(gA, sA[1], 64, CH_AE); STAGE2(gB, sB[1], 64, CH_BE);
    asm volatile("s_waitcnt vmcnt(4)" ::: "memory");
    __builtin_amdgcn_s_barrier();
    asm volatile("" ::: "memory");

    for (int t = 0; t < NT; ++t) {
        const int cur = t & 1;
        const ushort* At = sA[cur];
        const ushort* Bt = sB[cur];
        ushort* nxA = sA[cur ^ 1];
        ushort* nxB = sB[cur ^ 1];
        ushort* ccA = sA[cur];
        ushort* ccB = sB[cur];
        const int kb1 = (t + 1) * 64, kb2 = (t + 2) * 64;
        const bool st1 = (t + 1) < NT, st2 = (t + 2) < NT;

        PHASE(0, 0, if (st1) STAGE2(gA, nxA, kb1, CH_AL));
        PHASE(0, 1, if (st1) STAGE2(gB, nxB, kb1, CH_BL));
        PHASE(1, 0, if (st2) STAGE2(gA, ccA, kb2, CH_AE));
        PHASE(1, 1, if (st2) STAGE2(gB, ccB, kb2, CH_BE));

        if (st2) asm volatile("s_waitcnt vmcnt(4)" ::: "memory");
        else     asm volatile("s_waitcnt vmcnt(0)" ::: "memory");
        __builtin_amdgcn_s_barrier();
        asm volatile("" ::: "memory");
    }

    // ---- epilogue: C/D layout col=lane&15, row=(lane>>4)*4+reg ----
    const int rb = m0 + wm * 128 + ((lane >> 4) * 4);
    const int cb = n0 + wn * 64 + (lane & 15);
    if (EPI == 0) {
        ushort* Cw = (ushort*)C;
#pragma unroll
        for (int mi = 0; mi < 8; ++mi) {
#pragma unroll
            for (int r = 0; r < 4; ++r) {
                const int row = rb + mi * 16 + r;
                const float s = extra[row];
#pragma unroll
                for (int ni = 0; ni < 4; ++ni)
                    Cw[(size_t)row * N + cb + ni * 16] = f2bf(acc[mi][ni][r] * s);
            }
        }
    } else {
        float* Cf = (float*)C;
#pragma unroll
        for (int ni = 0; ni < 4; ++ni) {
            const float b = extra[cb + ni * 16];
#pragma unroll
            for (int mi = 0; mi < 8; ++mi) {
#pragma unroll
                for (int r = 0; r < 4; ++r) {
                    const int row = rb + mi * 16 + r;
                    Cf[(size_t)row * N + cb + ni * 16] = acc[mi][ni][r] + b;
                }
            }
        }
    }
}

// ---------- launch ----------
extern "C" void kernel_launch(void* const* d_in, const int* in_sizes, int n_in,
                              void* d_out, int out_size, void* d_ws, size_t ws_size,
                              hipStream_t stream) {
    const float* x     = (const float*)d_in[0];   // (4,2048,4096) f32
    const int*   widx  = (const int*)  d_in[1];   // (4096,4096) i32
    const float* wscal = (const float*)d_in[2];   // (4096,)
    const float* bias  = (const float*)d_in[3];   // (4096,)
    const float* rot   = (const float*)d_in[4];   // (4096,4096) f32
    const float* cb    = (const float*)d_in[5];   // (16,)
    float* out = (float*)d_out;                   // (4,2048,4096) f32

    constexpr size_t IN_F = 4096, OUT_F = 4096, MTOK = 8192;
    char* ws = (char*)d_ws;
    ushort* wq   = (ushort*)(ws);                 // 32 MiB: codebook[idx] bf16
    ushort* rbuf = (ushort*)(ws + 33554432);      // 32 MiB: rotation bf16
    ushort* xb   = (ushort*)(ws + 67108864);      // 64 MiB: x bf16
    ushort* wb   = (ushort*)(ws + 134217728);     // 32 MiB: dequantized W bf16
    (void)ws_size; (void)in_sizes; (void)n_in; (void)out_size;

    // converts (memory-bound)
    {
        int n4 = (int)(OUT_F * IN_F / 4);
        k_idx2bf<<<n4 / 256, 256, 0, stream>>>(widx, cb, wq, n4);
        k_f2bf<<<n4 / 256, 256, 0, stream>>>(rot, rbuf, n4);
        int n4x = (int)(MTOK * IN_F / 4);
        k_f2bf<<<n4x / 256, 256, 0, stream>>>(x, xb, n4x);
    }

    // GEMM A: W[o,j] = scale[o] * sum_i Wq[o,i] R[j,i]   (M=4096 -> 256 wgs)
    gemm256<0><<<dim3(256), 512, 0, stream>>>(wq, rbuf, (void*)wb, wscal);

    // GEMM B: out[m,o] = sum_j x[m,j] W[o,j] + bias[o]   (M=8192 -> 512 wgs)
    gemm256<1><<<dim3(512), 512, 0, stream>>>(xb, wb, (void*)out, bias);
}

// Round 3
// 606.747 us; speedup vs baseline: 1.0887x; 1.0887x over previous
//
#include <hip/hip_runtime.h>

// ---------- types ----------
typedef short short8 __attribute__((ext_vector_type(8)));   // 8 bf16 as i16
typedef float f32x4 __attribute__((ext_vector_type(4)));

#define GLOBAL_AS __attribute__((address_space(1)))
#define LDS_AS    __attribute__((address_space(3)))

__device__ __forceinline__ unsigned short f2bf(float f) {
    unsigned u = __builtin_bit_cast(unsigned, f);
    u += 0x7fffu + ((u >> 16) & 1u);          // round-to-nearest-even
    return (unsigned short)(u >> 16);
}

// ---------- convert kernels (memory-bound, vectorized) ----------
__global__ __launch_bounds__(256) void k_idx2bf(const int* __restrict__ idx,
                                                const float* __restrict__ cb,
                                                ushort* __restrict__ out, int n4) {
    int i = blockIdx.x * 256 + threadIdx.x;
    if (i >= n4) return;
    int4 v = reinterpret_cast<const int4*>(idx)[i];
    ushort4 o;
    o.x = f2bf(cb[v.x]); o.y = f2bf(cb[v.y]);
    o.z = f2bf(cb[v.z]); o.w = f2bf(cb[v.w]);
    reinterpret_cast<ushort4*>(out)[i] = o;
}

__global__ __launch_bounds__(256) void k_f2bf(const float* __restrict__ in,
                                              ushort* __restrict__ out, int n4) {
    int i = blockIdx.x * 256 + threadIdx.x;
    if (i >= n4) return;
    float4 v = reinterpret_cast<const float4*>(in)[i];
    ushort4 o;
    o.x = f2bf(v.x); o.y = f2bf(v.y); o.z = f2bf(v.z); o.w = f2bf(v.w);
    reinterpret_cast<ushort4*>(out)[i] = o;
}

// ---------- 256x256 8-phase bf16 gemm_bt: C[M,N] = A[M,K]*B[N,K]^T ----------
// 512 thr = 8 waves (2M x 4N), per-wave out 128x64, BK=64, 2 K-tile LDS dbuf
// (128 KiB). LDS swizzle: full 3-bit slot XOR, phys = byte ^ ((row&7)<<4)
// (each consecutive 8-lane group of a ds_read_b128 covers all 8 16B slots ->
// conflict-free). Applied as linear LDS dest + pre-swizzled GLOBAL source
// column + XOR'd ds_read address (both-sides involution, rule #21).
// Counted vmcnt(4) once per K-tile (region-phased prefetch, race-free):
//   ph1 Q(0,0) + stage t+1 A-late  -> buf[t+1&1]
//   ph2 Q(0,1) + stage t+1 B-late  -> buf[t+1&1]
//   ph3 Q(1,0) + stage t+2 A-early -> buf[t&1]   (A-early last read ph2)
//   ph4 Q(1,1) + stage t+2 B-early -> buf[t&1]   (B-early last read ph3)
// A-early rows: 0-63,128-191 (chunks 0-7,16-23); B-early rows: 0-31,64-95,
// 128-159,192-223 (chunks 0-3,8-11,16-19,24-27); chunk = 8 rows = 1024 B.

#define CH_AE(j) ((((j) & 8) << 1) | ((j) & 7))
#define CH_AL(j) (CH_AE(j) + 8)
#define CH_BE(j) ((((j) & 12) << 1) | ((j) & 3))
#define CH_BL(j) (CH_BE(j) + 4)

#define STAGE2(G, LDSBASE, KB, CF) do {                                         \
    const int c0_ = CF(2 * w), c1_ = CF(2 * w + 1);                             \
    __builtin_amdgcn_global_load_lds(                                           \
        (const GLOBAL_AS void*)((G) + (size_t)(c0_ * 8 + srow8) * 4096 + (KB) + scol), \
        (LDS_AS void*)((LDSBASE) + c0_ * 512), 16, 0, 0);                       \
    __builtin_amdgcn_global_load_lds(                                           \
        (const GLOBAL_AS void*)((G) + (size_t)(c1_ * 8 + srow8) * 4096 + (KB) + scol), \
        (LDS_AS void*)((LDSBASE) + c1_ * 512), 16, 0, 0);                       \
} while (0)

#define PHASE(MH, NH, ...) do {                                                 \
    short8 af_[2][4], bf_[2][2];                                                \
    _Pragma("unroll")                                                           \
    for (int k2 = 0; k2 < 2; ++k2) {                                            \
        _Pragma("unroll")                                                       \
        for (int mi = 0; mi < 4; ++mi) {                                        \
            const int lb = (arow + (MH) * 64 + mi * 16) * 128 + k2 * 64 + fkb;  \
            af_[k2][mi] = *reinterpret_cast<const short8*>((const char*)At + (lb ^ swb)); \
        }                                                                       \
        _Pragma("unroll")                                                       \
        for (int ni = 0; ni < 2; ++ni) {                                        \
            const int lb = (brow + (NH) * 32 + ni * 16) * 128 + k2 * 64 + fkb;  \
            bf_[k2][ni] = *reinterpret_cast<const short8*>((const char*)Bt + (lb ^ swb)); \
        }                                                                       \
    }                                                                           \
    __VA_ARGS__;                                                                \
    asm volatile("" ::: "memory");                                              \
    __builtin_amdgcn_s_barrier();                                               \
    __builtin_amdgcn_s_setprio(1);                                              \
    __builtin_amdgcn_sched_barrier(0);                                          \
    _Pragma("unroll")                                                           \
    for (int k2 = 0; k2 < 2; ++k2)                                              \
        _Pragma("unroll")                                                       \
        for (int mi = 0; mi < 4; ++mi)                                          \
            _Pragma("unroll")                                                   \
            for (int ni = 0; ni < 2; ++ni)                                      \
                acc[(MH) * 4 + mi][(NH) * 2 + ni] =                             \
                    __builtin_amdgcn_mfma_f32_16x16x32_bf16(                    \
                        af_[k2][mi], bf_[k2][ni], acc[(MH) * 4 + mi][(NH) * 2 + ni], 0, 0, 0); \
    __builtin_amdgcn_sched_barrier(0);                                          \
    __builtin_amdgcn_s_setprio(0);                                              \
    asm volatile("" ::: "memory");                                              \
    __builtin_amdgcn_s_barrier();                                               \
    asm volatile("" ::: "memory");                                              \
} while (0)

// EPI=0: C=bf16, val = acc * extra[row]; EPI=1: C=f32, val = acc + extra[col]
template <int EPI>
__global__ __launch_bounds__(512, 2) void gemm256(const ushort* __restrict__ A,
                                                  const ushort* __restrict__ B,
                                                  void* __restrict__ C,
                                                  const float* __restrict__ extra) {
    constexpr int K = 4096, N = 4096, NT = K / 64;
    __shared__ ushort sA[2][256 * 64];
    __shared__ ushort sB[2][256 * 64];

    const int tid  = threadIdx.x;
    const int w    = tid >> 6;
    const int lane = tid & 63;
    const int wm = w >> 2, wn = w & 3;

    // XCD-aware swizzle (nwg % 8 == 0 for both grids)
    const int nwg = gridDim.x;
    const int sw  = ((int)blockIdx.x & 7) * (nwg >> 3) + ((int)blockIdx.x >> 3);
    const int m0 = (sw >> 4) * 256;      // N/256 == 16 tiles per row
    const int n0 = (sw & 15) * 256;

    const ushort* gA = A + (size_t)m0 * K;
    const ushort* gB = B + (size_t)n0 * K;

    // staging lane geometry: dest = chunk*1024B + lane*16B (linear).
    // Physical slot s=lane&7 of row (r%8 = lane>>3) must hold logical slot
    // s ^ (r&7)  ->  pre-swizzle the global column (8 ushorts per slot).
    const int srow8 = lane >> 3;
    const int scol  = (((lane & 7) ^ (lane >> 3)) * 8);   // ushorts

    // fragment geometry (16x16x32: row=lane&15, k=(lane>>4)*8)
    const int fr   = lane & 15;
    const int fkb  = ((lane >> 4) & 3) * 16;          // byte offset along K
    const int swb  = (fr & 7) << 4;                   // read-side slot XOR
    const int arow = wm * 128 + fr;
    const int brow = wn * 64 + fr;

    f32x4 acc[8][4];
#pragma unroll
    for (int i = 0; i < 8; ++i)
#pragma unroll
        for (int j = 0; j < 4; ++j) acc[i][j] = (f32x4){0.f, 0.f, 0.f, 0.f};

    // ---- prologue: tile0 (all) -> buf0; tile1 (early) -> buf1 ----
    STAGE2(gA, sA[0], 0, CH_AE);  STAGE2(gB, sB[0], 0, CH_BE);
    STAGE2(gA, sA[0], 0, CH_AL);  STAGE2(gB, sB[0], 0, CH_BL);
    STAGE2(gA, sA[1], 64, CH_AE); STAGE2(gB, sB[1], 64, CH_BE);
    asm volatile("s_waitcnt vmcnt(4)" ::: "memory");
    __builtin_amdgcn_s_barrier();
    asm volatile("" ::: "memory");

    for (int t = 0; t < NT; ++t) {
        const int cur = t & 1;
        const ushort* At = sA[cur];
        const ushort* Bt = sB[cur];
        ushort* nxA = sA[cur ^ 1];
        ushort* nxB = sB[cur ^ 1];
        ushort* ccA = sA[cur];
        ushort* ccB = sB[cur];
        const int kb1 = (t + 1) * 64, kb2 = (t + 2) * 64;
        const bool st1 = (t + 1) < NT, st2 = (t + 2) < NT;

        PHASE(0, 0, if (st1) STAGE2(gA, nxA, kb1, CH_AL));
        PHASE(0, 1, if (st1) STAGE2(gB, nxB, kb1, CH_BL));
        PHASE(1, 0, if (st2) STAGE2(gA, ccA, kb2, CH_AE));
        PHASE(1, 1, if (st2) STAGE2(gB, ccB, kb2, CH_BE));

        if (st2) asm volatile("s_waitcnt vmcnt(4)" ::: "memory");
        else     asm volatile("s_waitcnt vmcnt(0)" ::: "memory");
        __builtin_amdgcn_s_barrier();
        asm volatile("" ::: "memory");
    }

    // ---- epilogue: C/D layout col=lane&15, row=(lane>>4)*4+reg ----
    const int rb = m0 + wm * 128 + ((lane >> 4) * 4);
    const int cb = n0 + wn * 64 + (lane & 15);
    if (EPI == 0) {
        ushort* Cw = (ushort*)C;
#pragma unroll
        for (int mi = 0; mi < 8; ++mi) {
#pragma unroll
            for (int r = 0; r < 4; ++r) {
                const int row = rb + mi * 16 + r;
                const float s = extra[row];
#pragma unroll
                for (int ni = 0; ni < 4; ++ni)
                    Cw[(size_t)row * N + cb + ni * 16] = f2bf(acc[mi][ni][r] * s);
            }
        }
    } else {
        float* Cf = (float*)C;
#pragma unroll
        for (int ni = 0; ni < 4; ++ni) {
            const float b = extra[cb + ni * 16];
#pragma unroll
            for (int mi = 0; mi < 8; ++mi) {
#pragma unroll
                for (int r = 0; r < 4; ++r) {
                    const int row = rb + mi * 16 + r;
                    Cf[(size_t)row * N + cb + ni * 16] = acc[mi][ni][r] + b;
                }
            }
        }
    }
}

// ---------- launch ----------
extern "C" void kernel_launch(void* const* d_in, const int* in_sizes, int n_in,
                              void* d_out, int out_size, void* d_ws, size_t ws_size,
                              hipStream_t stream) {
    const float* x     = (const float*)d_in[0];   // (4,2048,4096) f32
    const int*   widx  = (const int*)  d_in[1];   // (4096,4096) i32
    const float* wscal = (const float*)d_in[2];   // (4096,)
    const float* bias  = (const float*)d_in[3];   // (4096,)
    const float* rot   = (const float*)d_in[4];   // (4096,4096) f32
    const float* cb    = (const float*)d_in[5];   // (16,)
    float* out = (float*)d_out;                   // (4,2048,4096) f32

    constexpr size_t IN_F = 4096, OUT_F = 4096, MTOK = 8192;
    char* ws = (char*)d_ws;
    ushort* wq   = (ushort*)(ws);                 // 32 MiB: codebook[idx] bf16
    ushort* rbuf = (ushort*)(ws + 33554432);      // 32 MiB: rotation bf16
    ushort* xb   = (ushort*)(ws + 67108864);      // 64 MiB: x bf16
    ushort* wb   = (ushort*)(ws + 134217728);     // 32 MiB: dequantized W bf16
    (void)ws_size; (void)in_sizes; (void)n_in; (void)out_size;

    // converts (memory-bound)
    {
        int n4 = (int)(OUT_F * IN_F / 4);
        k_idx2bf<<<n4 / 256, 256, 0, stream>>>(widx, cb, wq, n4);
        k_f2bf<<<n4 / 256, 256, 0, stream>>>(rot, rbuf, n4);
        int n4x = (int)(MTOK * IN_F / 4);
        k_f2bf<<<n4x / 256, 256, 0, stream>>>(x, xb, n4x);
    }

    // GEMM A: W[o,j] = scale[o] * sum_i Wq[o,i] R[j,i]   (M=4096 -> 256 wgs)
    gemm256<0><<<dim3(256), 512, 0, stream>>>(wq, rbuf, (void*)wb, wscal);

    // GEMM B: out[m,o] = sum_j x[m,j] W[o,j] + bias[o]   (M=8192 -> 512 wgs)
    gemm256<1><<<dim3(512), 512, 0, stream>>>(xb, wb, (void*)out, bias);
}